// Round 2
// baseline (269.707 us; speedup 1.0000x reference)
//
#include <hip/hip_runtime.h>
#include <stdint.h>

#define IN_F   4096
#define OUT_F  4096
#define M_TOT  512
#define KT     (IN_F / 32)      // 128 global k-steps of 32
#define BN     32
#define BK     64
#define KSPLIT 2
#define KPB    (IN_F / KSPLIT)  // 2048 K per block
#define NITER  (KPB / BK)       // 32 rounds
#define NBUF   16               // LDS ring buffers (64 KB)

typedef unsigned short u16;
typedef __bf16 bf16x8 __attribute__((ext_vector_type(8)));
typedef float  f32x4  __attribute__((ext_vector_type(4)));

__device__ __forceinline__ u16 f2bf(float x) {
    unsigned u = __float_as_uint(x);
    u += 0x7FFFu + ((u >> 16) & 1u);   // round-to-nearest-even
    return (u16)(u >> 16);
}

// ---- pass 0: input fp32 -> bf16, MFMA-A-fragment order in workspace ----
// aws[((mt*KT + kt)*64 + lane)*8 + j] = in[mt*16 + (lane&15)][kt*32 + (lane>>4)*8 + j]
__global__ void pack_a_kernel(const float* __restrict__ in, u16* __restrict__ aws) {
    int t    = blockIdx.x * blockDim.x + threadIdx.x;  // 262144 threads
    int lane = t & 63;
    int kt   = (t >> 6) & (KT - 1);
    int mt   = t >> 13;
    int m = mt * 16 + (lane & 15);
    int k = kt * 32 + ((lane >> 4) << 3);
    const float* src = in + (size_t)m * IN_F + k;
    float4 a0 = *(const float4*)src;
    float4 a1 = *(const float4*)(src + 4);
    union { u16 u[8]; uint4 v; } pk;
    pk.u[0]=f2bf(a0.x); pk.u[1]=f2bf(a0.y); pk.u[2]=f2bf(a0.z); pk.u[3]=f2bf(a0.w);
    pk.u[4]=f2bf(a1.x); pk.u[5]=f2bf(a1.y); pk.u[6]=f2bf(a1.z); pk.u[7]=f2bf(a1.w);
    *(uint4*)(aws + (size_t)t * 8) = pk.v;
}

// ---- main: producer-consumer fused dequant+GEMM, no per-iteration barrier ----
// grid = 128 n-tiles x 2 k-halves = 256 blocks (1/CU), 1024 threads:
//   waves 0..7  = consumers (wave w owns m rows [w*64, w*64+64), n = BN tile)
//   waves 8..15 = producers (stream q/o/g -> dequant -> LDS ring)
__global__ __launch_bounds__(1024, 4) void qlinear_kernel(
    const u16*   __restrict__ aws,
    const int*   __restrict__ qw,
    const float* __restrict__ scales,
    const float* __restrict__ zeros,
    const float* __restrict__ outlier,
    const float* __restrict__ grad,
    float*       __restrict__ part)           // [KSPLIT][512][4096]
{
    // buffer = 4 frags (ks*2+nf) x 64 lanes x 8 bf16 = 4 KB
    __shared__ __align__(16) u16 Bsh[NBUF][4 * 64 * 8];
    __shared__ unsigned ready[NBUF];   // += 8 per completed fill
    __shared__ unsigned freed[NBUF];   // += 8 per completed consume

    const int tid  = threadIdx.x;
    const int lane = tid & 63;
    const int wv   = tid >> 6;                // 0..15

    if (tid < NBUF) { ready[tid] = 0; freed[tid] = 0; }
    __syncthreads();                          // only barrier in the kernel

    const int nblk  = blockIdx.x >> 1;
    const int khalf = blockIdx.x & 1;
    const int n0    = nblk * BN;
    const int k0    = khalf * KPB;

    if (wv >= 8) {
        // ================= producer =================
        const int pt   = tid - 512;           // 0..511
        const int row  = pt >> 4;             // 0..31 (weight row within tile)
        const int kc4  = (pt & 15) * 4;       // k offset within 64-wide tile
        const int orow = n0 + row;
        const float sr = scales[orow];
        const float c0 = -zeros[orow] * sr;   // w = q*s + (o*g - z*s)
        const size_t g0 = (size_t)orow * IN_F + k0 + kc4;

        const int j0    = kc4 & 7;            // 0 or 4
        const int frag  = ((kc4 >> 5) << 1) + (row >> 4);
        const int flane = (row & 15) | (((kc4 >> 3) & 3) << 4);
        const int doff  = (frag * 64 + flane) * 8 + j0;

        int4 qb[2]; float4 ob[2], gb[2];
        auto ld = [&](int r, int s) {
            size_t off = g0 + (size_t)r * BK;
            qb[s] = *(const int4*)  (qw      + off);
            ob[s] = *(const float4*)(outlier + off);
            gb[s] = *(const float4*)(grad    + off);
        };
        ld(0, 0);
        ld(1, 1);

        #pragma unroll 2
        for (int r = 0; r < NITER; ++r) {
            int b = r & (NBUF - 1);
            if (r >= NBUF) {
                unsigned need = 8u * (unsigned)(r / NBUF);
                while (__hip_atomic_load(&freed[b], __ATOMIC_ACQUIRE,
                                         __HIP_MEMORY_SCOPE_WORKGROUP) < need)
                    __builtin_amdgcn_s_sleep(1);
            }
            int s = r & 1;
            union { u16 u[4]; uint2 v; } pk;
            pk.u[0] = f2bf(fmaf((float)qb[s].x, sr, fmaf(ob[s].x, gb[s].x, c0)));
            pk.u[1] = f2bf(fmaf((float)qb[s].y, sr, fmaf(ob[s].y, gb[s].y, c0)));
            pk.u[2] = f2bf(fmaf((float)qb[s].z, sr, fmaf(ob[s].z, gb[s].z, c0)));
            pk.u[3] = f2bf(fmaf((float)qb[s].w, sr, fmaf(ob[s].w, gb[s].w, c0)));
            *(uint2*)(&Bsh[b][doff]) = pk.v;
            if (lane == 0)
                __hip_atomic_fetch_add(&ready[b], 1u, __ATOMIC_RELEASE,
                                       __HIP_MEMORY_SCOPE_WORKGROUP);
            if (r + 2 < NITER) ld(r + 2, s);
        }
    } else {
        // ================= consumer =================
        const int cw = wv;                    // m-stripe [cw*64, +64)
        const u16* abase = aws + ((size_t)(cw * 4) * KT + (size_t)khalf * (KPB / 32)) * 512
                               + (size_t)lane * 8;
        f32x4 acc[4][2] = {};

        #pragma unroll 1
        for (int r = 0; r < NITER; ++r) {
            int b = r & (NBUF - 1);
            unsigned need = 8u * (unsigned)(r / NBUF + 1);
            while (__hip_atomic_load(&ready[b], __ATOMIC_ACQUIRE,
                                     __HIP_MEMORY_SCOPE_WORKGROUP) < need)
                __builtin_amdgcn_s_sleep(1);

            const u16* bb = &Bsh[b][0];
            bf16x8 bfr[2][2], af[2][4];
            #pragma unroll
            for (int ks = 0; ks < 2; ++ks)
                #pragma unroll
                for (int nf = 0; nf < 2; ++nf)
                    bfr[ks][nf] = *(const bf16x8*)(bb + ((ks * 2 + nf) * 64 + lane) * 8);
            #pragma unroll
            for (int ks = 0; ks < 2; ++ks)
                #pragma unroll
                for (int mf = 0; mf < 4; ++mf)
                    af[ks][mf] = *(const bf16x8*)(abase + ((size_t)mf * KT + r * 2 + ks) * 512);
            #pragma unroll
            for (int ks = 0; ks < 2; ++ks)
                #pragma unroll
                for (int mf = 0; mf < 4; ++mf)
                    #pragma unroll
                    for (int nf = 0; nf < 2; ++nf)
                        acc[mf][nf] = __builtin_amdgcn_mfma_f32_16x16x32_bf16(
                            af[ks][mf], bfr[ks][nf], acc[mf][nf], 0, 0, 0);

            if (lane == 0)
                __hip_atomic_fetch_add(&freed[b], 1u, __ATOMIC_RELEASE,
                                       __HIP_MEMORY_SCOPE_WORKGROUP);
        }

        // epilogue: fp32 partials (C layout: col=lane&15, row=(lane>>4)*4+r)
        float* pout = part + (size_t)khalf * (M_TOT * OUT_F);
        const int cm0 = cw * 64 + ((lane >> 4) << 2);
        const int cn0 = n0 + (lane & 15);
        #pragma unroll
        for (int mf = 0; mf < 4; ++mf)
            #pragma unroll
            for (int nf = 0; nf < 2; ++nf) {
                float* op = pout + (size_t)(cm0 + mf * 16) * OUT_F + cn0 + nf * 16;
                #pragma unroll
                for (int rr = 0; rr < 4; ++rr)
                    op[(size_t)rr * OUT_F] = acc[mf][nf][rr];
            }
    }
}

// ---- reduce: out = bias + sum_k partial[k] ----
__global__ void reduce_kernel(const float4* __restrict__ part,
                              const float4* __restrict__ bias,
                              float4* __restrict__ out) {
    int idx = blockIdx.x * blockDim.x + threadIdx.x;   // 524288
    float4 s = bias[idx & (OUT_F / 4 - 1)];
    const int STRIDE = M_TOT * OUT_F / 4;
    #pragma unroll
    for (int k = 0; k < KSPLIT; ++k) {
        float4 p = part[(size_t)k * STRIDE + idx];
        s.x += p.x; s.y += p.y; s.z += p.z; s.w += p.w;
    }
    out[idx] = s;
}

extern "C" void kernel_launch(void* const* d_in, const int* in_sizes, int n_in,
                              void* d_out, int out_size, void* d_ws, size_t ws_size,
                              hipStream_t stream) {
    const float* input   = (const float*)d_in[0];
    const int*   qweight = (const int*)  d_in[1];
    const float* scales  = (const float*)d_in[2];
    const float* zeros   = (const float*)d_in[3];
    const float* outlier = (const float*)d_in[4];
    const float* grad    = (const float*)d_in[5];
    const float* bias    = (const float*)d_in[6];
    float* out = (float*)d_out;

    u16*   aws  = (u16*)d_ws;                               // 4 MB
    float* part = (float*)((char*)d_ws + (4u << 20));       // 16 MB

    pack_a_kernel<<<(M_TOT * IN_F / 8) / 256, 256, 0, stream>>>(input, aws);
    qlinear_kernel<<<(OUT_F / BN) * KSPLIT, 1024, 0, stream>>>(
        aws, qweight, scales, zeros, outlier, grad, part);
    reduce_kernel<<<(M_TOT * OUT_F / 4) / 256, 256, 0, stream>>>(
        (const float4*)part, (const float4*)bias, (float4*)out);
}

// Round 3
// 235.141 us; speedup vs baseline: 1.1470x; 1.1470x over previous
//
#include <hip/hip_runtime.h>
#include <stdint.h>

#define IN_F   4096
#define OUT_F  4096
#define M_TOT  512
#define KT     (IN_F / 32)      // 128 global k-steps of 32
#define BN     16               // weight rows per block
#define BK     128              // K per staging iteration
#define KSPLIT 2
#define KPB    (IN_F / KSPLIT)  // 2048 K per block
#define NITER  (KPB / BK)       // 16 iterations

typedef unsigned short u16;
typedef __bf16 bf16x8 __attribute__((ext_vector_type(8)));
typedef float  f32x4  __attribute__((ext_vector_type(4)));

__device__ __forceinline__ u16 f2bf(float x) {
    unsigned u = __float_as_uint(x);
    u += 0x7FFFu + ((u >> 16) & 1u);   // round-to-nearest-even
    return (u16)(u >> 16);
}

// ---- pass 0: input fp32 -> bf16, MFMA-A-fragment order in workspace ----
// aws[((mt*KT + kt)*64 + lane)*8 + j] = in[mt*16 + (lane&15)][kt*32 + (lane>>4)*8 + j]
__global__ void pack_a_kernel(const float* __restrict__ in, u16* __restrict__ aws) {
    int t    = blockIdx.x * blockDim.x + threadIdx.x;  // 262144 threads
    int lane = t & 63;
    int kt   = (t >> 6) & (KT - 1);
    int mt   = t >> 13;
    int m = mt * 16 + (lane & 15);
    int k = kt * 32 + ((lane >> 4) << 3);
    const float* src = in + (size_t)m * IN_F + k;
    float4 a0 = *(const float4*)src;
    float4 a1 = *(const float4*)(src + 4);
    union { u16 u[8]; uint4 v; } pk;
    pk.u[0]=f2bf(a0.x); pk.u[1]=f2bf(a0.y); pk.u[2]=f2bf(a0.z); pk.u[3]=f2bf(a0.w);
    pk.u[4]=f2bf(a1.x); pk.u[5]=f2bf(a1.y); pk.u[6]=f2bf(a1.z); pk.u[7]=f2bf(a1.w);
    *(uint4*)(aws + (size_t)t * 8) = pk.v;
}

// ---- main: fused dequant + GEMM; 512 blocks (256 n-tiles x 2 k-halves), 512 thr
// BM=512 (weights read once), BN=16, double-buffered LDS, 2 blocks/CU for overlap
__global__ __launch_bounds__(512, 4) void qlinear_kernel(
    const u16*   __restrict__ aws,
    const int*   __restrict__ qw,
    const float* __restrict__ scales,
    const float* __restrict__ zeros,
    const float* __restrict__ outlier,
    const float* __restrict__ grad,
    float*       __restrict__ part)           // [KSPLIT][512][4096]
{
    // buffer = 4 k-frags x 64 lanes x 8 bf16 = 4 KB; double-buffered = 8 KB
    __shared__ __align__(16) u16 Bsh[2][4 * 64 * 8];

    const int tid  = threadIdx.x;
    const int lane = tid & 63;
    const int wv   = tid >> 6;                // 0..7, m-stripe [wv*64, +64)

    const int nblk  = blockIdx.x >> 1;
    const int khalf = blockIdx.x & 1;
    const int n0    = nblk * BN;
    const int k0    = khalf * KPB;

    // ---- staging role: thread covers weight row (n0+srow), 4-wide k-chunk ----
    const int srow = tid >> 5;                // 0..15
    const int schk = tid & 31;                // 0..31 -> k_local = schk*4
    const int orow = n0 + srow;
    const float sr = scales[orow];
    const float c0 = -zeros[orow] * sr;       // w = q*s + (o*g - z*s)
    const size_t sg = (size_t)orow * IN_F + k0 + schk * 4;
    // B-frag layout (verified R1): frag ks (32-k), lane = n | (k_quad<<4), elem j = k&7
    const int sks   = schk >> 3;
    const int squad = (schk >> 1) & 3;
    const int j0    = (schk & 1) * 4;
    const int slane = srow | (squad << 4);
    const int doff  = (sks * 64 + slane) * 8 + j0;

    int4 qb[2]; float4 ob[2], gb[2];
    auto ld = [&](int it) {
        int s = it & 1;
        size_t off = sg + (size_t)it * BK;
        qb[s] = *(const int4*)  (qw      + off);
        ob[s] = *(const float4*)(outlier + off);
        gb[s] = *(const float4*)(grad    + off);
    };
    auto st = [&](int it) {
        int s = it & 1;
        union { u16 u[4]; uint2 v; } pk;
        pk.u[0] = f2bf(fmaf((float)qb[s].x, sr, fmaf(ob[s].x, gb[s].x, c0)));
        pk.u[1] = f2bf(fmaf((float)qb[s].y, sr, fmaf(ob[s].y, gb[s].y, c0)));
        pk.u[2] = f2bf(fmaf((float)qb[s].z, sr, fmaf(ob[s].z, gb[s].z, c0)));
        pk.u[3] = f2bf(fmaf((float)qb[s].w, sr, fmaf(ob[s].w, gb[s].w, c0)));
        *(uint2*)(&Bsh[it & 1][doff]) = pk.v;
    };

    // A fragment base: frag (mf, d) at abase + (mf*KT + d)*512, d = global 32-k step
    const u16* abase = aws + ((size_t)(wv * 4) * KT + khalf * (KPB / 32)) * 512
                           + (size_t)lane * 8;

    f32x4 acc[4] = {};

    ld(0);
    st(0);
    ld(1);
    __syncthreads();

    for (int it = 0; it < NITER; ++it) {
        const u16* bb = &Bsh[it & 1][0];
        bf16x8 bfr[4];
        #pragma unroll
        for (int ks = 0; ks < 4; ++ks)
            bfr[ks] = *(const bf16x8*)(bb + (ks * 64 + lane) * 8);

        #pragma unroll
        for (int ks = 0; ks < 4; ++ks) {
            #pragma unroll
            for (int mf = 0; mf < 4; ++mf) {
                bf16x8 af = *(const bf16x8*)(abase + ((size_t)mf * KT + it * 4 + ks) * 512);
                acc[mf] = __builtin_amdgcn_mfma_f32_16x16x32_bf16(af, bfr[ks], acc[mf], 0, 0, 0);
            }
        }

        if (it + 1 < NITER) st(it + 1);       // slot (it+1)&1 -> buf (it+1)&1
        if (it + 2 < NITER) ld(it + 2);
        __syncthreads();
    }

    // ---- epilogue: fp32 partials (C layout: col=lane&15, row=(lane>>4)*4+r) ----
    float* pout = part + (size_t)khalf * (M_TOT * OUT_F);
    const int cm0 = wv * 64 + ((lane >> 4) << 2);
    const int cn  = n0 + (lane & 15);
    #pragma unroll
    for (int mf = 0; mf < 4; ++mf) {
        #pragma unroll
        for (int r = 0; r < 4; ++r)
            pout[(size_t)(cm0 + mf * 16 + r) * OUT_F + cn] = acc[mf][r];
    }
}

// ---- reduce: out = bias + sum_k partial[k] ----
__global__ void reduce_kernel(const float4* __restrict__ part,
                              const float4* __restrict__ bias,
                              float4* __restrict__ out) {
    int idx = blockIdx.x * blockDim.x + threadIdx.x;   // 524288
    float4 s = bias[idx & (OUT_F / 4 - 1)];
    const int STRIDE = M_TOT * OUT_F / 4;
    #pragma unroll
    for (int k = 0; k < KSPLIT; ++k) {
        float4 p = part[(size_t)k * STRIDE + idx];
        s.x += p.x; s.y += p.y; s.z += p.z; s.w += p.w;
    }
    out[idx] = s;
}

extern "C" void kernel_launch(void* const* d_in, const int* in_sizes, int n_in,
                              void* d_out, int out_size, void* d_ws, size_t ws_size,
                              hipStream_t stream) {
    const float* input   = (const float*)d_in[0];
    const int*   qweight = (const int*)  d_in[1];
    const float* scales  = (const float*)d_in[2];
    const float* zeros   = (const float*)d_in[3];
    const float* outlier = (const float*)d_in[4];
    const float* grad    = (const float*)d_in[5];
    const float* bias    = (const float*)d_in[6];
    float* out = (float*)d_out;

    u16*   aws  = (u16*)d_ws;                               // 4 MB
    float* part = (float*)((char*)d_ws + (4u << 20));       // 16 MB

    pack_a_kernel<<<(M_TOT * IN_F / 8) / 256, 256, 0, stream>>>(input, aws);
    qlinear_kernel<<<(OUT_F / BN) * KSPLIT, 512, 0, stream>>>(
        aws, qweight, scales, zeros, outlier, grad, part);
    reduce_kernel<<<(M_TOT * OUT_F / 4) / 256, 256, 0, stream>>>(
        (const float4*)part, (const float4*)bias, (float4*)out);
}

// Round 4
// 220.010 us; speedup vs baseline: 1.2259x; 1.0688x over previous
//
#include <hip/hip_runtime.h>
#include <stdint.h>

#define IN_F   4096
#define OUT_F  4096
#define M_TOT  512
#define KT     (IN_F / 32)      // 128 global 32-wide k-steps
#define BN     64               // weight rows per block
#define BK     64               // K per staging iteration
#define KSPLIT 4
#define KPB    (IN_F / KSPLIT)  // 1024 K per block
#define NITER  (KPB / BK)       // 16 iterations

typedef unsigned short u16;
typedef __bf16 bf16x8 __attribute__((ext_vector_type(8)));
typedef float  f32x4  __attribute__((ext_vector_type(4)));
typedef int    i32x4  __attribute__((ext_vector_type(4)));
typedef float  fv4    __attribute__((ext_vector_type(4)));

__device__ __forceinline__ u16 f2bf(float x) {
    unsigned u = __float_as_uint(x);
    u += 0x7FFFu + ((u >> 16) & 1u);   // round-to-nearest-even
    return (u16)(u >> 16);
}

// ---- pass 0: input fp32 -> bf16, MFMA-A-fragment order in workspace ----
// aws[((mt*KT + kt)*64 + lane)*8 + j] = in[mt*16 + (lane&15)][kt*32 + (lane>>4)*8 + j]
__global__ void pack_a_kernel(const float* __restrict__ in, u16* __restrict__ aws) {
    int t    = blockIdx.x * blockDim.x + threadIdx.x;  // 262144 threads
    int lane = t & 63;
    int kt   = (t >> 6) & (KT - 1);
    int mt   = t >> 13;
    int m = mt * 16 + (lane & 15);
    int k = kt * 32 + ((lane >> 4) << 3);
    const float* src = in + (size_t)m * IN_F + k;
    float4 a0 = *(const float4*)src;
    float4 a1 = *(const float4*)(src + 4);
    union { u16 u[8]; uint4 v; } pk;
    pk.u[0]=f2bf(a0.x); pk.u[1]=f2bf(a0.y); pk.u[2]=f2bf(a0.z); pk.u[3]=f2bf(a0.w);
    pk.u[4]=f2bf(a1.x); pk.u[5]=f2bf(a1.y); pk.u[6]=f2bf(a1.z); pk.u[7]=f2bf(a1.w);
    *(uint4*)(aws + (size_t)t * 8) = pk.v;
}

// ---- main: fused dequant + GEMM; 256 blocks (64 n-tiles x 4 k-quarters), 1024 thr
// BM=512 (weights read exactly once), BN=64. Weights/partials are non-temporal so
// the 4 MB packed-A array stays L2-resident (A re-reads were the R1-R3 bottleneck).
__global__ __launch_bounds__(1024, 4) void qlinear_kernel(
    const u16*   __restrict__ aws,
    const int*   __restrict__ qw,
    const float* __restrict__ scales,
    const float* __restrict__ zeros,
    const float* __restrict__ outlier,
    const float* __restrict__ grad,
    float*       __restrict__ part)           // [KSPLIT][512][4096]
{
    // buffer = 8 frags (ks*4+nf) x 64 lanes x 8 bf16 = 8 KB; double-buffered 16 KB
    __shared__ __align__(16) u16 Bsh[2][8 * 64 * 8];

    const int tid  = threadIdx.x;
    const int lane = tid & 63;
    const int wv   = tid >> 6;                // 0..15, m-stripe [wv*32, +32)

    const int nblk = blockIdx.x >> 2;
    const int kq   = blockIdx.x & 3;
    const int n0   = nblk * BN;
    const int k0   = kq * KPB;

    // ---- staging role: thread covers weight row (n0+srow), 4-wide k-chunk ----
    const int srow = tid >> 4;                // 0..63
    const int schk = tid & 15;                // k_local = schk*4 (0..63)
    const int orow = n0 + srow;
    const float sr = scales[orow];
    const float c0 = -zeros[orow] * sr;       // w = q*s + (o*g - z*s)
    const size_t sg = (size_t)orow * IN_F + k0 + schk * 4;
    // B-frag coords (layout verified R1/R3): frag = ks*4+nf, lane = (n&15)|(quad<<4)
    const int sks   = schk >> 3;              // k_local>>5
    const int squad = (schk >> 1) & 3;        // (k_local>>3)&3
    const int j0    = (schk & 1) * 4;         // k_local&7 base
    const int snf   = srow >> 4;
    const int slane = (srow & 15) | (squad << 4);
    const int doff  = ((sks * 4 + snf) * 64 + slane) * 8 + j0;

    i32x4 qb[2]; fv4 ob[2], gb[2];
    auto ld = [&](int it) {
        int s = it & 1;
        size_t off = sg + (size_t)it * BK;
        qb[s] = __builtin_nontemporal_load((const i32x4*)(qw      + off));
        ob[s] = __builtin_nontemporal_load((const fv4*)  (outlier + off));
        gb[s] = __builtin_nontemporal_load((const fv4*)  (grad    + off));
    };
    auto st = [&](int it) {
        int s = it & 1;
        union { u16 u[4]; uint2 v; } pk;
        pk.u[0] = f2bf(fmaf((float)qb[s].x, sr, fmaf(ob[s].x, gb[s].x, c0)));
        pk.u[1] = f2bf(fmaf((float)qb[s].y, sr, fmaf(ob[s].y, gb[s].y, c0)));
        pk.u[2] = f2bf(fmaf((float)qb[s].z, sr, fmaf(ob[s].z, gb[s].z, c0)));
        pk.u[3] = f2bf(fmaf((float)qb[s].w, sr, fmaf(ob[s].w, gb[s].w, c0)));
        *(uint2*)(&Bsh[it & 1][doff]) = pk.v;
    };

    // A fragment base: frag (mf, d) at abase + (mf*KT + d)*512, d = global 32-k step
    const u16* abase = aws + ((size_t)(wv * 2) * KT + kq * (KPB / 32)) * 512
                           + (size_t)lane * 8;

    f32x4 acc[2][4] = {};

    ld(0);
    st(0);
    ld(1);
    __syncthreads();

    for (int it = 0; it < NITER; ++it) {
        // A loads first (longest latency), cached (temporal) — L2-resident
        bf16x8 af[2][2];
        #pragma unroll
        for (int ks = 0; ks < 2; ++ks)
            #pragma unroll
            for (int mf = 0; mf < 2; ++mf)
                af[ks][mf] = *(const bf16x8*)(abase + ((size_t)mf * KT + it * 2 + ks) * 512);

        const u16* bb = &Bsh[it & 1][0];
        #pragma unroll
        for (int ks = 0; ks < 2; ++ks) {
            bf16x8 bfr[4];
            #pragma unroll
            for (int nf = 0; nf < 4; ++nf)
                bfr[nf] = *(const bf16x8*)(bb + (((ks * 4 + nf) * 64) + lane) * 8);
            #pragma unroll
            for (int mf = 0; mf < 2; ++mf)
                #pragma unroll
                for (int nf = 0; nf < 4; ++nf)
                    acc[mf][nf] = __builtin_amdgcn_mfma_f32_16x16x32_bf16(
                        af[ks][mf], bfr[nf], acc[mf][nf], 0, 0, 0);
        }

        if (it + 1 < NITER) st(it + 1);
        if (it + 2 < NITER) ld(it + 2);
        __syncthreads();
    }

    // ---- epilogue: fp32 partials, non-temporal (write-once-read-once) ----
    float* pout = part + (size_t)kq * (M_TOT * OUT_F);
    const int cm0 = wv * 32 + ((lane >> 4) << 2);
    const int cn  = n0 + (lane & 15);
    #pragma unroll
    for (int mf = 0; mf < 2; ++mf)
        #pragma unroll
        for (int nf = 0; nf < 4; ++nf)
            #pragma unroll
            for (int r = 0; r < 4; ++r)
                __builtin_nontemporal_store(
                    acc[mf][nf][r],
                    pout + (size_t)(cm0 + mf * 16 + r) * OUT_F + cn + nf * 16);
}

// ---- reduce: out = bias + sum_k partial[k] ----
__global__ void reduce_kernel(const fv4* __restrict__ part,
                              const fv4* __restrict__ bias,
                              fv4* __restrict__ out) {
    int idx = blockIdx.x * blockDim.x + threadIdx.x;   // 524288
    fv4 s = bias[idx & (OUT_F / 4 - 1)];
    const int STRIDE = M_TOT * OUT_F / 4;
    #pragma unroll
    for (int k = 0; k < KSPLIT; ++k) {
        fv4 p = __builtin_nontemporal_load(part + (size_t)k * STRIDE + idx);
        s += p;
    }
    out[idx] = s;
}

extern "C" void kernel_launch(void* const* d_in, const int* in_sizes, int n_in,
                              void* d_out, int out_size, void* d_ws, size_t ws_size,
                              hipStream_t stream) {
    const float* input   = (const float*)d_in[0];
    const int*   qweight = (const int*)  d_in[1];
    const float* scales  = (const float*)d_in[2];
    const float* zeros   = (const float*)d_in[3];
    const float* outlier = (const float*)d_in[4];
    const float* grad    = (const float*)d_in[5];
    const float* bias    = (const float*)d_in[6];
    float* out = (float*)d_out;

    u16*   aws  = (u16*)d_ws;                               // 4 MB
    float* part = (float*)((char*)d_ws + (4u << 20));       // 32 MB

    pack_a_kernel<<<(M_TOT * IN_F / 8) / 256, 256, 0, stream>>>(input, aws);
    qlinear_kernel<<<(OUT_F / BN) * KSPLIT, 1024, 0, stream>>>(
        aws, qweight, scales, zeros, outlier, grad, part);
    reduce_kernel<<<(M_TOT * OUT_F / 4) / 256, 256, 0, stream>>>(
        (const fv4*)part, (const fv4*)bias, (fv4*)out);
}